// Round 10
// baseline (258.606 us; speedup 1.0000x reference)
//
#include <hip/hip_runtime.h>
#include <hip/hip_bf16.h>
#include <stdint.h>

typedef __bf16 bf16;
typedef __bf16 v8bf __attribute__((ext_vector_type(8)));
typedef __bf16 v4bf __attribute__((ext_vector_type(4)));
typedef float  v4f  __attribute__((ext_vector_type(4)));

#define TSEQ   2048
#define HIDDIM 2048
#define NHEAD  16
#define HDIM   128

// async global->LDS, 16B per lane, LDS dest = wave-uniform base + lane*16 (m97 pattern)
__device__ __forceinline__ void async16(void* lds, const void* g)
{
    __builtin_amdgcn_global_load_lds(
        (__attribute__((address_space(1))) void*)(uintptr_t)g,
        (__attribute__((address_space(3))) void*)(unsigned int)(uintptr_t)lds,
        16, 0, 0);
}

// ---------------- f32 -> bf16 bulk convert: 4 matrices of TSEQ*HIDDIM ----------------
// (Wo is no longer converted: gemm_out reads it in f32 directly.)
__global__ __launch_bounds__(256) void conv5(const float* __restrict__ s0, bf16* __restrict__ d0,
                                             const float* __restrict__ s1, bf16* __restrict__ d1,
                                             const float* __restrict__ s2, bf16* __restrict__ d2,
                                             const float* __restrict__ s3, bf16* __restrict__ d3)
{
    const float* src; bf16* dst;
    switch (blockIdx.y) {
        case 0: src = s0; dst = d0; break;
        case 1: src = s1; dst = d1; break;
        case 2: src = s2; dst = d2; break;
        default: src = s3; dst = d3; break;
    }
    const size_t i = ((size_t)blockIdx.x * 256 + threadIdx.x) * 8;
    const float4 a = *(const float4*)(src + i);
    const float4 b = *(const float4*)(src + i + 4);
    v8bf o;
    o[0] = (bf16)a.x; o[1] = (bf16)a.y; o[2] = (bf16)a.z; o[3] = (bf16)a.w;
    o[4] = (bf16)b.x; o[5] = (bf16)b.y; o[6] = (bf16)b.z; o[7] = (bf16)b.w;
    *(v8bf*)(dst + i) = o;
}

// ============ 128x384-tile 6-phase NT GEMM + fused ReBased fmap + fused V-transpose ===========
// C[2048,6144] = A * Wcat^T. Grid 16x16 = 256 blocks = 1/CU. 512 thr = 8 waves (2M x 4N);
// per-wave 64 rows x {nh*128 + wn*32 + nj*16} cols (nh 0..2), acc[4][6]. BK=64, double-
// buffered 128 KiB LDS via global_load_lds. 16 MFMA/phase, counted vmcnt (never 0 in loop).
// Bank-deswizzle both-sides: slot p of a 128B row holds logical slot p ^ (row&7).
// NOTE: 128x384 is the UNIQUE full-fill geometry with head-aligned BN (fused LN needs
// BN % 128 == 0); structure pinned at ~60us after 4 rounds of phase surgery.

#define PBAR() do { __builtin_amdgcn_sched_barrier(0); __builtin_amdgcn_s_barrier(); \
                    __builtin_amdgcn_sched_barrier(0); } while (0)

// stage one 128-row x 64-col unit (16 KB): 2 issues/thread, wave-uniform LDS base
#define STU(ldst, gsrc) do { \
    async16((ldst) + w*512,        (gsrc) + (size_t)(w*8 + (l>>3))*2048); \
    async16((ldst) + 4096 + w*512, (gsrc) + (size_t)(64 + w*8 + (l>>3))*2048); \
} while (0)

// A-frags of buffer buf -> a[0..3][0..1] (8 ds_read_b128)
#define RDA(buf) do { _Pragma("unroll") \
    for (int mi_ = 0; mi_ < 4; ++mi_) { \
        const bf16* p_ = &sA[(buf)*8192 + (wm*64 + mi_*16 + lr)*64]; \
        a[mi_][0] = *(const v8bf*)(p_ + c0); \
        a[mi_][1] = *(const v8bf*)(p_ + c1); } } while (0)

// B-frags for chunk nh of buffer buf -> b[0..1][0..1] (4 ds_read_b128)
#define RDB(buf, nh) do { _Pragma("unroll") \
    for (int nj_ = 0; nj_ < 2; ++nj_) { \
        const bf16* p_ = &sB[(buf)*24576 + ((nh)*128 + wn*32 + nj_*16 + lr)*64]; \
        b[nj_][0] = *(const v8bf*)(p_ + c0); \
        b[nj_][1] = *(const v8bf*)(p_ + c1); } } while (0)

// 16 MFMA: 4 mi x 2 nj x 2 k for column-group nh
#define MQ(nh) do { _Pragma("unroll") \
    for (int mi_ = 0; mi_ < 4; ++mi_) { _Pragma("unroll") \
        for (int nj_ = 0; nj_ < 2; ++nj_) { \
            acc[mi_][(nh)*2+nj_] = __builtin_amdgcn_mfma_f32_16x16x32_bf16( \
                a[mi_][0], b[nj_][0], acc[mi_][(nh)*2+nj_], 0, 0, 0); \
            acc[mi_][(nh)*2+nj_] = __builtin_amdgcn_mfma_f32_16x16x32_bf16( \
                a[mi_][1], b[nj_][1], acc[mi_][(nh)*2+nj_], 0, 0, 0); \
        } } } while (0)

#define VMC(n) asm volatile("s_waitcnt vmcnt(" #n ")" ::: "memory")

__global__ __launch_bounds__(512, 2) void gemm_qkv384(const bf16* __restrict__ A,
    const bf16* __restrict__ Wcat, bf16* __restrict__ qb, bf16* __restrict__ kb,
    bf16* __restrict__ vt, const float* __restrict__ gamma, const float* __restrict__ beta)
{
    __shared__ __attribute__((aligned(16))) bf16 sA[2*8192];    // 2 x 128x64 = 32 KB
    __shared__ __attribute__((aligned(16))) bf16 sB[2*24576];   // 2 x 384x64 = 96 KB
    const int n0g = blockIdx.x * 384;         // over concat(Wq,Wk,Wv) rows (6144)
    const int m0  = blockIdx.y * 128;

    const int tid = threadIdx.x, l = tid & 63, w = tid >> 6;    // 8 waves
    const int wm = w >> 2, wn = w & 3;                          // 2x4 wave grid
    const int quad = l >> 4, lr = l & 15;
    const int scol = ((l & 7) ^ ((l >> 3) & 7)) * 8;            // staged source col
    const int c0 = ((quad    ) ^ (lr & 7)) * 8;                 // read deswizzle
    const int c1 = ((quad + 4) ^ (lr & 7)) * 8;

    const bf16* Ag = A    + (size_t)m0  * 2048 + scol;
    const bf16* Bg = Wcat + (size_t)n0g * 2048 + scol;

    v4f  acc[4][6] = {};
    v8bf a[4][2], b[2][2];

    // prologue (matches steady-state issue history): A(0) B0(0) B1(0) B2(0)
    // A(1) B0(1) B1(1) = 14 issues; B2(1) is staged at Ph0 of iter 0.
    STU(&sA[0],           Ag);
    STU(&sB[0],           Bg);
    STU(&sB[8192],        Bg + (size_t)128*2048);
    STU(&sB[16384],       Bg + (size_t)256*2048);
    STU(&sA[8192],        Ag + 64);
    STU(&sB[24576],       Bg + 64);
    STU(&sB[24576+8192],  Bg + (size_t)128*2048 + 64);
    VMC(10);                                   // A(0),B0(0) landed
    __builtin_amdgcn_s_barrier();
    __builtin_amdgcn_sched_barrier(0);

#pragma unroll 1
    for (int it = 0; it < 16; ++it) {          // tiles T=2it (buf0), T+1 (buf1)
        const int k1 =  it*128 + 64;                // tile T+1 (max 1984, no wrap)
        const int k2 = (it*128 + 128) & 2047;       // tile T+2 (wrap harmless last iter)
        const int k3 = (it*128 + 192) & 2047;       // tile T+3

        // Ph0: read A,B0(buf0); stage B2(T+1)->buf1 (read Ph5: 5-phase gap)
        RDA(0); RDB(0, 0);
        STU(&sB[24576+16384], Bg + (size_t)256*2048 + k1);
        PBAR(); __builtin_amdgcn_s_setprio(1); MQ(0); __builtin_amdgcn_s_setprio(0);
        VMC(10); PBAR();
        // Ph1: read B1(buf0); stage A,B0(T+2)->buf0 (read next Ph0: 5)
        RDB(0, 1);
        STU(&sA[0], Ag + k2);
        STU(&sB[0], Bg + k2);
        PBAR(); __builtin_amdgcn_s_setprio(1); MQ(1); __builtin_amdgcn_s_setprio(0);
        VMC(12); PBAR();
        // Ph2: read B2(buf0); stage B1(T+2)->buf0 (read next Ph1: 5)
        RDB(0, 2);
        STU(&sB[8192], Bg + (size_t)128*2048 + k2);
        PBAR(); __builtin_amdgcn_s_setprio(1); MQ(2); __builtin_amdgcn_s_setprio(0);
        VMC(10); PBAR();
        // Ph3: read A,B0(buf1); stage B2(T+2)->buf0 (read next Ph2: 5)
        RDA(1); RDB(1, 0);
        STU(&sB[16384], Bg + (size_t)256*2048 + k2);
        PBAR(); __builtin_amdgcn_s_setprio(1); MQ(0); __builtin_amdgcn_s_setprio(0);
        VMC(10); PBAR();
        // Ph4: read B1(buf1); stage A,B0(T+3)->buf1 (read next Ph3: 5)
        RDB(1, 1);
        STU(&sA[8192],  Ag + k3);
        STU(&sB[24576], Bg + k3);
        PBAR(); __builtin_amdgcn_s_setprio(1); MQ(1); __builtin_amdgcn_s_setprio(0);
        VMC(12); PBAR();
        // Ph5: read B2(buf1); stage B1(T+3)->buf1 (read next Ph4: 5)
        RDB(1, 2);
        STU(&sB[24576+8192], Bg + (size_t)128*2048 + k3);
        PBAR(); __builtin_amdgcn_s_setprio(1); MQ(2); __builtin_amdgcn_s_setprio(0);
        VMC(10); PBAR();
    }
    VMC(0);                                    // drain wrap refetches
    __syncthreads();                           // all waves done -> sA/sB dead

    // ---------------- fused epilogue: LN (q/k heads) via LDS tile, V transposed ----------
    bf16* sT = sB;                             // [128][136] bf16 tile (34 KB)
    const int erow = tid >> 2;                 // 0..127 (row within block)
    const int ecol = (tid & 3) * 32;           // 4 threads/row, 32 cols each
    float gv[32], bv[32];
#pragma unroll
    for (int i = 0; i < 8; ++i) {
        *(float4*)&gv[i*4] = *(const float4*)(gamma + ecol + i*4);
        *(float4*)&bv[i*4] = *(const float4*)(beta  + ecol + i*4);
    }

#pragma unroll
    for (int nh = 0; nh < 3; ++nh) {
        const int colg0 = n0g + nh*128;
        const int which = colg0 >> 11;         // block-uniform
        if (which == 2) {
            // V head: vt[c][t], lane holds 4 consecutive t -> 8B stores
#pragma unroll
            for (int mi = 0; mi < 4; ++mi) {
                const int row = m0 + wm*64 + mi*16 + quad*4;
#pragma unroll
                for (int jj = 0; jj < 2; ++jj) {
                    const int c = (colg0 & 2047) + wn*32 + jj*16 + lr;
                    v4bf pk;
#pragma unroll
                    for (int r = 0; r < 4; ++r) pk[r] = (bf16)acc[mi][nh*2+jj][r];
                    *(v4bf*)(vt + (size_t)c*2048 + row) = pk;
                }
            }
        } else {
            // stage this head's fragments to sT (32 x ds_write_b16, ~2-way conflicts)
#pragma unroll
            for (int mi = 0; mi < 4; ++mi) {
                const int row = wm*64 + mi*16 + quad*4;
#pragma unroll
                for (int jj = 0; jj < 2; ++jj) {
                    const int col = wn*32 + jj*16 + lr;
#pragma unroll
                    for (int r = 0; r < 4; ++r)
                        sT[(row + r)*136 + col] = (bf16)acc[mi][nh*2+jj][r];
                }
            }
            __syncthreads();
            // LN: 4 threads per row (lane^1, lane^2 shfl combine)
            float x[32];
            float s = 0.f, q = 0.f;
#pragma unroll
            for (int i = 0; i < 4; ++i) {
                const v8bf v = *(const v8bf*)&sT[erow*136 + ecol + i*8];
#pragma unroll
                for (int k = 0; k < 8; ++k) {
                    const float xv = (float)v[k] * gv[i*8+k] + bv[i*8+k];
                    x[i*8+k] = xv; s += xv; q += xv*xv;
                }
            }
            s += __shfl_xor(s, 1); q += __shfl_xor(q, 1);
            s += __shfl_xor(s, 2); q += __shfl_xor(q, 2);
            const float mu = s * (1.0f/128.0f);
            float var = q * (1.0f/128.0f) - mu*mu;
            var = fmaxf(var, 0.0f);
            bf16* Cb = (which == 0) ? qb : kb;
            const float qs = (which == 0) ? 0.08838834764831845f : 1.0f; // D^-0.5 on q
            const float rstd = rsqrtf(var + 1e-5f) * qs;
            bf16* dst = Cb + (size_t)(m0 + erow)*2048 + (colg0 & 2047) + ecol;
#pragma unroll
            for (int i = 0; i < 4; ++i) {
                v8bf o;
#pragma unroll
                for (int k = 0; k < 8; ++k)
                    o[k] = (bf16)((x[i*8+k] - mu) * rstd);
                *(v8bf*)(dst + i*8) = o;
            }
            __syncthreads();                   // sT reused by next LN head
        }
    }
}

// ======= 128x128-tile NT GEMM (fp32 out): full-chip 16x16 grid, 2-K-tiles/phase =======
// B (Wo) is read in f32 and converted during reg-staging: f32 loads issue at phase
// start, cvt+ds_write after the MFMA block (VMC(0) is already there) -> fully hidden.
#define RDO(aa, bb, buf) do { _Pragma("unroll") \
    for (int mi_ = 0; mi_ < 4; ++mi_) { \
        const bf16* p_ = &sA[(buf)*8192 + (wm*64 + mi_*16 + lr)*64]; \
        aa[mi_][0] = *(const v8bf*)(p_ + c0); \
        aa[mi_][1] = *(const v8bf*)(p_ + c1); } \
    _Pragma("unroll") \
    for (int nj_ = 0; nj_ < 2; ++nj_) { \
        const bf16* p_ = &sB[(buf)*8192 + (wn*32 + nj_*16 + lr)*64]; \
        bb[nj_][0] = *(const v8bf*)(p_ + c0); \
        bb[nj_][1] = *(const v8bf*)(p_ + c1); } } while (0)

#define MQO(aa, bb) do { _Pragma("unroll") \
    for (int mi_ = 0; mi_ < 4; ++mi_) { _Pragma("unroll") \
        for (int nj_ = 0; nj_ < 2; ++nj_) { \
            acc[mi_][nj_] = __builtin_amdgcn_mfma_f32_16x16x32_bf16( \
                aa[mi_][0], bb[nj_][0], acc[mi_][nj_], 0, 0, 0); \
            acc[mi_][nj_] = __builtin_amdgcn_mfma_f32_16x16x32_bf16( \
                aa[mi_][1], bb[nj_][1], acc[mi_][nj_], 0, 0, 0); \
        } } } while (0)

// load one 128x64 B-unit (f32 source) into regs: 4 float4 per thread
#define LDBF(fbuf, gsrcf) do { _Pragma("unroll") \
    for (int u_ = 0; u_ < 2; ++u_) { \
        const float* sp_ = (gsrcf) + (size_t)(u_*64 + w*8 + (l>>3))*2048 + scol; \
        fbuf[u_][0] = *(const float4*)(sp_); \
        fbuf[u_][1] = *(const float4*)(sp_ + 4); } } while (0)

// convert + write that unit to LDS (2 ds_write_b128 per thread)
#define WRBF(ldst, fbuf) do { _Pragma("unroll") \
    for (int u_ = 0; u_ < 2; ++u_) { \
        v8bf t_; \
        t_[0] = (bf16)fbuf[u_][0].x; t_[1] = (bf16)fbuf[u_][0].y; \
        t_[2] = (bf16)fbuf[u_][0].z; t_[3] = (bf16)fbuf[u_][0].w; \
        t_[4] = (bf16)fbuf[u_][1].x; t_[5] = (bf16)fbuf[u_][1].y; \
        t_[6] = (bf16)fbuf[u_][1].z; t_[7] = (bf16)fbuf[u_][1].w; \
        *(v8bf*)((ldst) + u_*4096 + w*512 + l*8) = t_; } } while (0)

__global__ __launch_bounds__(512, 2) void gemm_out(const bf16* __restrict__ A,
    const float* __restrict__ Bf, float* __restrict__ C)
{
    __shared__ __attribute__((aligned(16))) bf16 sA[4*8192];   // 64 KB: buf t&3 of 128x64
    __shared__ __attribute__((aligned(16))) bf16 sB[4*8192];   // 64 KB
    const int m0 = blockIdx.y * 128, n0 = blockIdx.x * 128;
    const int tid = threadIdx.x, l = tid & 63, w = tid >> 6;   // 8 waves
    const int wm = w >> 2, wn = w & 3;                         // 2x4 wave grid
    const int quad = l >> 4, lr = l & 15;
    const int scol = ((l & 7) ^ ((l >> 3) & 7)) * 8;           // staged source col
    const int c0 = ((quad    ) ^ (lr & 7)) * 8;                // read deswizzle
    const int c1 = ((quad + 4) ^ (lr & 7)) * 8;

    const bf16*  Ag = A  + (size_t)m0 * 2048 + scol;
    const float* Bg = Bf + (size_t)n0 * 2048;                  // scol applied in LDBF

    v4f  acc[4][2] = {};
    v8bf a0[4][2], b0[2][2], a1[4][2], b1[2][2];
    float4 fb0[2][2], fb1[2][2];

    // prologue: tiles 0,1 -> bufs 0,1 (A async; B f32 reg-staged)
    LDBF(fb0, Bg); LDBF(fb1, Bg + 64);
    STU(&sA[0],    Ag);
    STU(&sA[8192], Ag + 64);
    VMC(0);
    WRBF(&sB[0], fb0); WRBF(&sB[8192], fb1);
    __syncthreads();

#pragma unroll 2
    for (int p = 0; p < 16; ++p) {
        const int e = (p & 1) * 2;                 // read pair base buf (0 or 2)
        const int o = 2 - e;                       // stage pair base buf
        const int ks0 = ((2*p + 2) & 31) * 64;     // tile 2p+2 (wrap refetch harmless)
        const int ks1 = ((2*p + 3) & 31) * 64;     // tile 2p+3
        LDBF(fb0, Bg + ks0);                       // f32 B loads issue early
        LDBF(fb1, Bg + ks1);
        RDO(a0, b0, e);
        RDO(a1, b1, e + 1);
        STU(&sA[o*8192],     Ag + ks0);
        STU(&sA[(o+1)*8192], Ag + ks1);
        PBAR();
        __builtin_amdgcn_s_setprio(1);
        MQO(a0, b0);
        MQO(a1, b1);
        __builtin_amdgcn_s_setprio(0);
        VMC(0);                                    // A async + B f32 all returned
        WRBF(&sB[o*8192],     fb0);                // cvt+write hidden behind MFMA
        WRBF(&sB[(o+1)*8192], fb1);
        PBAR();
    }

#pragma unroll
    for (int mi = 0; mi < 4; ++mi) {
        const int row = m0 + wm*64 + mi*16 + quad*4;
#pragma unroll
        for (int nj = 0; nj < 2; ++nj) {
            const int col = n0 + wn*32 + nj*16 + lr;
#pragma unroll
            for (int r = 0; r < 4; ++r)
                C[(size_t)(row + r)*HIDDIM + col] = acc[mi][nj][r];
        }
    }
}

// ---------------- quadratic causal attention, paired 64-row q-tiles (r7-exact) ----------
// Balance fix: block handles tiles (31-p) and (p) -> exactly 33 chunks per block.
// grid = 16 pairs x 16 heads = 256 blocks (1/CU), 512 threads = 8 waves.
// sS rows wave-private (r8's cross-wave split regressed); no XCD swizzle (r9: <= neutral).
__global__ __launch_bounds__(512, 2) void attn(const bf16* __restrict__ qb,
                                               const bf16* __restrict__ kb,
                                               const bf16* __restrict__ vt,
                                               bf16* __restrict__ ob)
{
    __shared__ __attribute__((aligned(16))) bf16 sK[2*64*136];   // per-buf [s][d], pad 8
    __shared__ __attribute__((aligned(16))) bf16 sV[2*128*72];   // per-buf [d][s], pad 8
    __shared__ __attribute__((aligned(16))) bf16 sS[2*64*72];    // per-group [q][s], pad 8
    __shared__ __attribute__((aligned(16))) float sO[64*129];    // combine scratch, pad 1
    __shared__ __attribute__((aligned(16))) float sZ[64*17];

    const int h    = blockIdx.y;
    const int pr   = blockIdx.x;              // pair index 0..15
    const int tid  = threadIdx.x, lane = tid & 63;
    const int w    = tid >> 6;                // 0..7
    const int g    = w >> 2;                  // chunk group 0/1
    const int ww   = w & 3;                   // wave within group
    const int quad = lane >> 4, lr = lane & 15;
    const int rs   = tid >> 4;                // staging row 0..31 (x4 passes)
    const int cs   = (tid & 15) * 8;          // staging col 0..120

#pragma unroll
    for (int ti = 0; ti < 2; ++ti) {
        const int tile = ti ? pr : (31 - pr);
        const int nch  = tile + 1;

        // Q fragments (A-layout): wave owns q-rows [tile*64 + ww*16, +16)
        v8bf qa[4];
        {
            const bf16* q0 = qb + (size_t)(tile*64 + ww*16 + lr)*HIDDIM + h*HDIM + quad*8;
#pragma unroll
            for (int ks = 0; ks < 4; ++ks)
                qa[ks] = *(const v8bf*)(q0 + ks*32);
        }

        v4f  o[8] = {};
        float z[4] = {0.f, 0.f, 0.f, 0.f};

        v8bf curK[4], curV[4], nxtK[4], nxtV[4];
#pragma unroll
        for (int p = 0; p < 4; ++p) {
            curK[p] = *(const v8bf*)(kb + (size_t)(rs + p*32)*HIDDIM + h*HDIM + cs);
            curV[p] = *(const v8bf*)(vt + (size_t)(h*HDIM + rs + p*32)*HIDDIM + cs);
        }

        for (int ich = 0; ich < nch; ich += 2) {
            __syncthreads();                  // prev-chunk LDS reads done
#pragma unroll
            for (int p = 0; p < 4; ++p) {
                const int r = rs + p*32;      // kv row within pair [0,128)
                *(v8bf*)&sK[(r>>6)*8704 + (r&63)*136 + cs] = curK[p];
            }
#pragma unroll
            for (int p = 0; p < 4; ++p)       // cs selects buffer (col>=64 -> buf 1)
                *(v8bf*)&sV[(cs>>6)*9216 + (rs + p*32)*72 + (cs & 63)] = curV[p];

            if (ich + 2 < nch) {              // prefetch next pair (overlaps compute)
                const int s1 = (ich + 2) * 64;
#pragma unroll
                for (int p = 0; p < 4; ++p) {
                    nxtK[p] = *(const v8bf*)(kb + (size_t)(s1 + rs + p*32)*HIDDIM + h*HDIM + cs);
                    nxtV[p] = *(const v8bf*)(vt + (size_t)(h*HDIM + rs + p*32)*HIDDIM + s1 + cs);
                }
            }
            __syncthreads();                  // tiles visible

            const int ch = ich + g;
            if (ch < nch) {
                const bf16* sKg = &sK[g*8704];
                const bf16* sVg = &sV[g*9216];
                bf16*       sSg = &sS[g*4608];
                const bool  diag = (ch == tile);
                const int   s0   = ch * 64;

                // QK^T -> square/mask -> z, sS (sS rows wave-private)
                v8bf kbf[4][4];
#pragma unroll
                for (int nj = 0; nj < 4; ++nj)
#pragma unroll
                    for (int ks = 0; ks < 4; ++ks)
                        kbf[nj][ks] = *(const v8bf*)&sKg[(nj*16 + lr)*136 + ks*32 + quad*8];
                const int row_l = ww*16 + quad*4;
                const int qg    = tile*64 + row_l;
#pragma unroll
                for (int nj = 0; nj < 4; ++nj) {
                    v4f s4 = {0.f, 0.f, 0.f, 0.f};
#pragma unroll
                    for (int ks = 0; ks < 4; ++ks)
                        s4 = __builtin_amdgcn_mfma_f32_16x16x32_bf16(qa[ks], kbf[nj][ks], s4, 0, 0, 0);
                    const int col = nj*16 + lr;
                    const int sg  = s0 + col;
#pragma unroll
                    for (int r = 0; r < 4; ++r) {
                        float val = s4[r] * s4[r];
                        if (diag && (sg > qg + r)) val = 0.0f;
                        const bf16 vb16 = (bf16)val;
                        z[r] += (float)vb16;           // consistent with what multiplies V
                        sSg[(row_l + r)*72 + col] = vb16;
                    }
                }

                // O += S * V
#pragma unroll
                for (int ks = 0; ks < 2; ++ks) {
                    const v8bf sa = *(const v8bf*)&sSg[(ww*16 + lr)*72 + ks*32 + quad*8];
#pragma unroll
                    for (int nd = 0; nd < 8; ++nd) {
                        const v8bf vbf = *(const v8bf*)&sVg[(nd*16 + lr)*72 + ks*32 + quad*8];
                        o[nd] = __builtin_amdgcn_mfma_f32_16x16x32_bf16(sa, vbf, o[nd], 0, 0, 0);
                    }
                }
            }

            if (ich + 2 < nch) {
#pragma unroll
                for (int p = 0; p < 4; ++p) { curK[p] = nxtK[p]; curV[p] = nxtV[p]; }
            }
        }

        // cross-group combine: group 1 dumps partial O,z; group 0 adds + epilogue.
        const int row_l = ww*16 + quad*4;
        __syncthreads();
        if (g == 1) {
#pragma unroll
            for (int nd = 0; nd < 8; ++nd)
#pragma unroll
                for (int r = 0; r < 4; ++r)
                    sO[(row_l + r)*129 + nd*16 + lr] = o[nd][r];
#pragma unroll
            for (int r = 0; r < 4; ++r)
                sZ[(row_l + r)*17 + lr] = z[r];
        }
        __syncthreads();
        if (g == 0) {
#pragma unroll
            for (int nd = 0; nd < 8; ++nd)
#pragma unroll
                for (int r = 0; r < 4; ++r)
                    o[nd][r] += sO[(row_l + r)*129 + nd*16 + lr];
#pragma unroll
            for (int r = 0; r < 4; ++r) {
                float zz = z[r] + sZ[(row_l + r)*17 + lr];
                zz += __shfl_xor(zz, 1); zz += __shfl_xor(zz, 2);
                zz += __shfl_xor(zz, 4); zz += __shfl_xor(zz, 8);
                z[r] = zz + 1e-5f;
            }
            const size_t rbase = (size_t)(tile*64 + row_l)*HIDDIM + h*HDIM;
#pragma unroll
            for (int nd = 0; nd < 8; ++nd) {
                const int col = nd*16 + lr;
#pragma unroll
                for (int r = 0; r < 4; ++r)
                    ob[rbase + (size_t)r*HIDDIM + col] = (bf16)(o[nd][r] / z[r]);
            }
        }
    }
}

extern "C" void kernel_launch(void* const* d_in, const int* in_sizes, int n_in,
                              void* d_out, int out_size, void* d_ws, size_t ws_size,
                              hipStream_t stream)
{
    const float* hs    = (const float*)d_in[0];
    const float* Wq    = (const float*)d_in[1];
    const float* Wk    = (const float*)d_in[2];
    const float* Wv    = (const float*)d_in[3];
    const float* Wo    = (const float*)d_in[4];
    const float* gamma = (const float*)d_in[5];
    const float* beta  = (const float*)d_in[6];
    float* outp = (float*)d_out;

    const size_t MAT = (size_t)TSEQ * HIDDIM;     // 4.19M elems

    // ws layout (bf16 slots of 8.39 MB): hs_b(0), Wcat(1-3, q/k/v contiguous), vt(5).
    // Slot 4 free (Wo no longer converted — gemm_out reads f32 Wo directly).
    // qb/kb live in d_out (dead once gemm_out overwrites it with the final fp32
    // output). ob aliases hs_b (dead after gemm_qkv384).
    bf16* ws   = (bf16*)d_ws;
    bf16* hs_b = ws + 0*MAT;
    bf16* ob   = hs_b;                            // alias: hs_b dead after gemm_qkv384
    bf16* Wq_b = ws + 1*MAT;                      // Wcat base
    bf16* Wk_b = ws + 2*MAT;
    bf16* Wv_b = ws + 3*MAT;
    bf16* vt   = ws + 5*MAT;
    bf16* qb   = (bf16*)d_out;
    bf16* kb   = (bf16*)d_out + MAT;

    conv5<<<dim3(2048, 4), 256, 0, stream>>>(hs, hs_b, Wq, Wq_b, Wk, Wk_b, Wv, Wv_b);
    gemm_qkv384<<<dim3(16, 16), 512, 0, stream>>>(hs_b, Wq_b, qb, kb, vt, gamma, beta);
    attn<<<dim3(16, 16), 512, 0, stream>>>(qb, kb, vt, ob);
    gemm_out<<<dim3(16, 16), 512, 0, stream>>>(ob, Wo, outp);
}

// Round 11
// 246.852 us; speedup vs baseline: 1.0476x; 1.0476x over previous
//
#include <hip/hip_runtime.h>
#include <hip/hip_bf16.h>
#include <stdint.h>

typedef __bf16 bf16;
typedef __bf16 v8bf __attribute__((ext_vector_type(8)));
typedef __bf16 v4bf __attribute__((ext_vector_type(4)));
typedef float  v4f  __attribute__((ext_vector_type(4)));

#define TSEQ   2048
#define HIDDIM 2048
#define NHEAD  16
#define HDIM   128

// async global->LDS, 16B per lane, LDS dest = wave-uniform base + lane*16 (m97 pattern)
__device__ __forceinline__ void async16(void* lds, const void* g)
{
    __builtin_amdgcn_global_load_lds(
        (__attribute__((address_space(1))) void*)(uintptr_t)g,
        (__attribute__((address_space(3))) void*)(unsigned int)(uintptr_t)lds,
        16, 0, 0);
}

// ---------------- f32 -> bf16 bulk convert: 5 matrices of TSEQ*HIDDIM ----------------
__global__ __launch_bounds__(256) void conv5(const float* __restrict__ s0, bf16* __restrict__ d0,
                                             const float* __restrict__ s1, bf16* __restrict__ d1,
                                             const float* __restrict__ s2, bf16* __restrict__ d2,
                                             const float* __restrict__ s3, bf16* __restrict__ d3,
                                             const float* __restrict__ s4, bf16* __restrict__ d4)
{
    const float* src; bf16* dst;
    switch (blockIdx.y) {
        case 0: src = s0; dst = d0; break;
        case 1: src = s1; dst = d1; break;
        case 2: src = s2; dst = d2; break;
        case 3: src = s3; dst = d3; break;
        default: src = s4; dst = d4; break;
    }
    const size_t i = ((size_t)blockIdx.x * 256 + threadIdx.x) * 8;
    const float4 a = *(const float4*)(src + i);
    const float4 b = *(const float4*)(src + i + 4);
    v8bf o;
    o[0] = (bf16)a.x; o[1] = (bf16)a.y; o[2] = (bf16)a.z; o[3] = (bf16)a.w;
    o[4] = (bf16)b.x; o[5] = (bf16)b.y; o[6] = (bf16)b.z; o[7] = (bf16)b.w;
    *(v8bf*)(dst + i) = o;
}

// ============ 128x384-tile 6-phase NT GEMM + fused ReBased fmap + fused V-transpose ===========
// C[2048,6144] = A * Wcat^T. Grid 16x16 = 256 blocks = 1/CU. 512 thr = 8 waves (2M x 4N);
// per-wave 64 rows x {nh*128 + wn*32 + nj*16} cols (nh 0..2), acc[4][6]. BK=64, double-
// buffered 128 KiB LDS via global_load_lds. 16 MFMA/phase, counted vmcnt (never 0 in loop).
// Bank-deswizzle both-sides: slot p of a 128B row holds logical slot p ^ (row&7).
// EPILOGUE: per LN head, stage the 128x128 fragment to an LDS tile (sB is dead),
// then 4 threads/row do the LN with vector reads + 2-step shfl + 16B coalesced stores.
// V heads: store transposed directly into vt[c][t] (8B stores, L2 write-combines).

#define PBAR() do { __builtin_amdgcn_sched_barrier(0); __builtin_amdgcn_s_barrier(); \
                    __builtin_amdgcn_sched_barrier(0); } while (0)

// stage one 128-row x 64-col unit (16 KB): 2 issues/thread, wave-uniform LDS base
#define STU(ldst, gsrc) do { \
    async16((ldst) + w*512,        (gsrc) + (size_t)(w*8 + (l>>3))*2048); \
    async16((ldst) + 4096 + w*512, (gsrc) + (size_t)(64 + w*8 + (l>>3))*2048); \
} while (0)

// A-frags of buffer buf -> a[0..3][0..1] (8 ds_read_b128)
#define RDA(buf) do { _Pragma("unroll") \
    for (int mi_ = 0; mi_ < 4; ++mi_) { \
        const bf16* p_ = &sA[(buf)*8192 + (wm*64 + mi_*16 + lr)*64]; \
        a[mi_][0] = *(const v8bf*)(p_ + c0); \
        a[mi_][1] = *(const v8bf*)(p_ + c1); } } while (0)

// B-frags for chunk nh of buffer buf -> b[0..1][0..1] (4 ds_read_b128)
#define RDB(buf, nh) do { _Pragma("unroll") \
    for (int nj_ = 0; nj_ < 2; ++nj_) { \
        const bf16* p_ = &sB[(buf)*24576 + ((nh)*128 + wn*32 + nj_*16 + lr)*64]; \
        b[nj_][0] = *(const v8bf*)(p_ + c0); \
        b[nj_][1] = *(const v8bf*)(p_ + c1); } } while (0)

// 16 MFMA: 4 mi x 2 nj x 2 k for column-group nh
#define MQ(nh) do { _Pragma("unroll") \
    for (int mi_ = 0; mi_ < 4; ++mi_) { _Pragma("unroll") \
        for (int nj_ = 0; nj_ < 2; ++nj_) { \
            acc[mi_][(nh)*2+nj_] = __builtin_amdgcn_mfma_f32_16x16x32_bf16( \
                a[mi_][0], b[nj_][0], acc[mi_][(nh)*2+nj_], 0, 0, 0); \
            acc[mi_][(nh)*2+nj_] = __builtin_amdgcn_mfma_f32_16x16x32_bf16( \
                a[mi_][1], b[nj_][1], acc[mi_][(nh)*2+nj_], 0, 0, 0); \
        } } } while (0)

#define VMC(n) asm volatile("s_waitcnt vmcnt(" #n ")" ::: "memory")

__global__ __launch_bounds__(512, 2) void gemm_qkv384(const bf16* __restrict__ A,
    const bf16* __restrict__ Wcat, bf16* __restrict__ qb, bf16* __restrict__ kb,
    bf16* __restrict__ vt, const float* __restrict__ gamma, const float* __restrict__ beta)
{
    __shared__ __attribute__((aligned(16))) bf16 sA[2*8192];    // 2 x 128x64 = 32 KB
    __shared__ __attribute__((aligned(16))) bf16 sB[2*24576];   // 2 x 384x64 = 96 KB
    const int n0g = blockIdx.x * 384;         // over concat(Wq,Wk,Wv) rows (6144)
    const int m0  = blockIdx.y * 128;

    const int tid = threadIdx.x, l = tid & 63, w = tid >> 6;    // 8 waves
    const int wm = w >> 2, wn = w & 3;                          // 2x4 wave grid
    const int quad = l >> 4, lr = l & 15;
    const int scol = ((l & 7) ^ ((l >> 3) & 7)) * 8;            // staged source col
    const int c0 = ((quad    ) ^ (lr & 7)) * 8;                 // read deswizzle
    const int c1 = ((quad + 4) ^ (lr & 7)) * 8;

    const bf16* Ag = A    + (size_t)m0  * 2048 + scol;
    const bf16* Bg = Wcat + (size_t)n0g * 2048 + scol;

    v4f  acc[4][6] = {};
    v8bf a[4][2], b[2][2];

    // prologue (matches steady-state issue history): A(0) B0(0) B1(0) B2(0)
    // A(1) B0(1) B1(1) = 14 issues; B2(1) is staged at Ph0 of iter 0.
    STU(&sA[0],           Ag);
    STU(&sB[0],           Bg);
    STU(&sB[8192],        Bg + (size_t)128*2048);
    STU(&sB[16384],       Bg + (size_t)256*2048);
    STU(&sA[8192],        Ag + 64);
    STU(&sB[24576],       Bg + 64);
    STU(&sB[24576+8192],  Bg + (size_t)128*2048 + 64);
    VMC(10);                                   // A(0),B0(0) landed
    __builtin_amdgcn_s_barrier();
    __builtin_amdgcn_sched_barrier(0);

#pragma unroll 1
    for (int it = 0; it < 16; ++it) {          // tiles T=2it (buf0), T+1 (buf1)
        const int k1 =  it*128 + 64;                // tile T+1 (max 1984, no wrap)
        const int k2 = (it*128 + 128) & 2047;       // tile T+2 (wrap harmless last iter)
        const int k3 = (it*128 + 192) & 2047;       // tile T+3

        // Ph0: read A,B0(buf0); stage B2(T+1)->buf1 (read Ph5: 5-phase gap)
        RDA(0); RDB(0, 0);
        STU(&sB[24576+16384], Bg + (size_t)256*2048 + k1);
        PBAR(); __builtin_amdgcn_s_setprio(1); MQ(0); __builtin_amdgcn_s_setprio(0);
        VMC(10); PBAR();
        // Ph1: read B1(buf0); stage A,B0(T+2)->buf0 (read next Ph0: 5)
        RDB(0, 1);
        STU(&sA[0], Ag + k2);
        STU(&sB[0], Bg + k2);
        PBAR(); __builtin_amdgcn_s_setprio(1); MQ(1); __builtin_amdgcn_s_setprio(0);
        VMC(12); PBAR();
        // Ph2: read B2(buf0); stage B1(T+2)->buf0 (read next Ph1: 5)
        RDB(0, 2);
        STU(&sB[8192], Bg + (size_t)128*2048 + k2);
        PBAR(); __builtin_amdgcn_s_setprio(1); MQ(2); __builtin_amdgcn_s_setprio(0);
        VMC(10); PBAR();
        // Ph3: read A,B0(buf1); stage B2(T+2)->buf0 (read next Ph2: 5)
        RDA(1); RDB(1, 0);
        STU(&sB[16384], Bg + (size_t)256*2048 + k2);
        PBAR(); __builtin_amdgcn_s_setprio(1); MQ(0); __builtin_amdgcn_s_setprio(0);
        VMC(10); PBAR();
        // Ph4: read B1(buf1); stage A,B0(T+3)->buf1 (read next Ph3: 5)
        RDB(1, 1);
        STU(&sA[8192],  Ag + k3);
        STU(&sB[24576], Bg + k3);
        PBAR(); __builtin_amdgcn_s_setprio(1); MQ(1); __builtin_amdgcn_s_setprio(0);
        VMC(12); PBAR();
        // Ph5: read B2(buf1); stage B1(T+3)->buf1 (read next Ph4: 5)
        RDB(1, 2);
        STU(&sB[24576+8192], Bg + (size_t)128*2048 + k3);
        PBAR(); __builtin_amdgcn_s_setprio(1); MQ(2); __builtin_amdgcn_s_setprio(0);
        VMC(10); PBAR();
    }
    VMC(0);                                    // drain wrap refetches
    __syncthreads();                           // all waves done -> sA/sB dead

    // ---------------- fused epilogue: LN (q/k heads) via LDS tile, V transposed ----------
    bf16* sT = sB;                             // [128][136] bf16 tile (34 KB)
    const int erow = tid >> 2;                 // 0..127 (row within block)
    const int ecol = (tid & 3) * 32;           // 4 threads/row, 32 cols each
    float gv[32], bv[32];
#pragma unroll
    for (int i = 0; i < 8; ++i) {
        *(float4*)&gv[i*4] = *(const float4*)(gamma + ecol + i*4);
        *(float4*)&bv[i*4] = *(const float4*)(beta  + ecol + i*4);
    }

#pragma unroll
    for (int nh = 0; nh < 3; ++nh) {
        const int colg0 = n0g + nh*128;
        const int which = colg0 >> 11;         // block-uniform
        if (which == 2) {
            // V head: vt[c][t], lane holds 4 consecutive t -> 8B stores
#pragma unroll
            for (int mi = 0; mi < 4; ++mi) {
                const int row = m0 + wm*64 + mi*16 + quad*4;
#pragma unroll
                for (int jj = 0; jj < 2; ++jj) {
                    const int c = (colg0 & 2047) + wn*32 + jj*16 + lr;
                    v4bf pk;
#pragma unroll
                    for (int r = 0; r < 4; ++r) pk[r] = (bf16)acc[mi][nh*2+jj][r];
                    *(v4bf*)(vt + (size_t)c*2048 + row) = pk;
                }
            }
        } else {
            // stage this head's fragments to sT (32 x ds_write_b16, ~2-way conflicts)
#pragma unroll
            for (int mi = 0; mi < 4; ++mi) {
                const int row = wm*64 + mi*16 + quad*4;
#pragma unroll
                for (int jj = 0; jj < 2; ++jj) {
                    const int col = wn*32 + jj*16 + lr;
#pragma unroll
                    for (int r = 0; r < 4; ++r)
                        sT[(row + r)*136 + col] = (bf16)acc[mi][nh*2+jj][r];
                }
            }
            __syncthreads();
            // LN: 4 threads per row (lane^1, lane^2 shfl combine)
            float x[32];
            float s = 0.f, q = 0.f;
#pragma unroll
            for (int i = 0; i < 4; ++i) {
                const v8bf v = *(const v8bf*)&sT[erow*136 + ecol + i*8];
#pragma unroll
                for (int k = 0; k < 8; ++k) {
                    const float xv = (float)v[k] * gv[i*8+k] + bv[i*8+k];
                    x[i*8+k] = xv; s += xv; q += xv*xv;
                }
            }
            s += __shfl_xor(s, 1); q += __shfl_xor(q, 1);
            s += __shfl_xor(s, 2); q += __shfl_xor(q, 2);
            const float mu = s * (1.0f/128.0f);
            float var = q * (1.0f/128.0f) - mu*mu;
            var = fmaxf(var, 0.0f);
            bf16* Cb = (which == 0) ? qb : kb;
            const float qs = (which == 0) ? 0.08838834764831845f : 1.0f; // D^-0.5 on q
            const float rstd = rsqrtf(var + 1e-5f) * qs;
            bf16* dst = Cb + (size_t)(m0 + erow)*2048 + (colg0 & 2047) + ecol;
#pragma unroll
            for (int i = 0; i < 4; ++i) {
                v8bf o;
#pragma unroll
                for (int k = 0; k < 8; ++k)
                    o[k] = (bf16)((x[i*8+k] - mu) * rstd);
                *(v8bf*)(dst + i*8) = o;
            }
            __syncthreads();                   // sT reused by next LN head
        }
    }
}

// ======= 128x128-tile NT GEMM (fp32 out): full-chip 16x16 grid, 2-K-tiles/phase =======
#define RDO(aa, bb, buf) do { _Pragma("unroll") \
    for (int mi_ = 0; mi_ < 4; ++mi_) { \
        const bf16* p_ = &sA[(buf)*8192 + (wm*64 + mi_*16 + lr)*64]; \
        aa[mi_][0] = *(const v8bf*)(p_ + c0); \
        aa[mi_][1] = *(const v8bf*)(p_ + c1); } \
    _Pragma("unroll") \
    for (int nj_ = 0; nj_ < 2; ++nj_) { \
        const bf16* p_ = &sB[(buf)*8192 + (wn*32 + nj_*16 + lr)*64]; \
        bb[nj_][0] = *(const v8bf*)(p_ + c0); \
        bb[nj_][1] = *(const v8bf*)(p_ + c1); } } while (0)

#define MQO(aa, bb) do { _Pragma("unroll") \
    for (int mi_ = 0; mi_ < 4; ++mi_) { _Pragma("unroll") \
        for (int nj_ = 0; nj_ < 2; ++nj_) { \
            acc[mi_][nj_] = __builtin_amdgcn_mfma_f32_16x16x32_bf16( \
                aa[mi_][0], bb[nj_][0], acc[mi_][nj_], 0, 0, 0); \
            acc[mi_][nj_] = __builtin_amdgcn_mfma_f32_16x16x32_bf16( \
                aa[mi_][1], bb[nj_][1], acc[mi_][nj_], 0, 0, 0); \
        } } } while (0)

__global__ __launch_bounds__(512, 2) void gemm_out(const bf16* __restrict__ A,
    const bf16* __restrict__ B, float* __restrict__ C)
{
    __shared__ __attribute__((aligned(16))) bf16 sA[4*8192];   // 64 KB: buf t&3 of 128x64
    __shared__ __attribute__((aligned(16))) bf16 sB[4*8192];   // 64 KB
    const int m0 = blockIdx.y * 128, n0 = blockIdx.x * 128;
    const int tid = threadIdx.x, l = tid & 63, w = tid >> 6;   // 8 waves
    const int wm = w >> 2, wn = w & 3;                         // 2x4 wave grid
    const int quad = l >> 4, lr = l & 15;
    const int scol = ((l & 7) ^ ((l >> 3) & 7)) * 8;           // staged source col
    const int c0 = ((quad    ) ^ (lr & 7)) * 8;                // read deswizzle
    const int c1 = ((quad + 4) ^ (lr & 7)) * 8;

    const bf16* Ag = A + (size_t)m0 * 2048 + scol;
    const bf16* Bg = B + (size_t)n0 * 2048 + scol;

    v4f  acc[4][2] = {};
    v8bf a0[4][2], b0[2][2], a1[4][2], b1[2][2];

    // prologue: tiles 0,1 -> bufs 0,1
    STU(&sA[0],    Ag);      STU(&sB[0],    Bg);
    STU(&sA[8192], Ag + 64); STU(&sB[8192], Bg + 64);
    VMC(0);
    __builtin_amdgcn_s_barrier();
    __builtin_amdgcn_sched_barrier(0);

#pragma unroll 2
    for (int p = 0; p < 16; ++p) {
        const int e = (p & 1) * 2;                 // read pair base buf (0 or 2)
        const int o = 2 - e;                       // stage pair base buf
        const int ks0 = ((2*p + 2) & 31) * 64;     // tile 2p+2 (wrap refetch harmless)
        const int ks1 = ((2*p + 3) & 31) * 64;     // tile 2p+3
        RDO(a0, b0, e);
        RDO(a1, b1, e + 1);
        STU(&sA[o*8192],       Ag + ks0);  STU(&sB[o*8192],       Bg + ks0);
        STU(&sA[(o+1)*8192],   Ag + ks1);  STU(&sB[(o+1)*8192],   Bg + ks1);
        PBAR();
        __builtin_amdgcn_s_setprio(1);
        MQO(a0, b0);
        MQO(a1, b1);
        __builtin_amdgcn_s_setprio(0);
        VMC(0);
        PBAR();
    }

#pragma unroll
    for (int mi = 0; mi < 4; ++mi) {
        const int row = m0 + wm*64 + mi*16 + quad*4;
#pragma unroll
        for (int nj = 0; nj < 2; ++nj) {
            const int col = n0 + wn*32 + nj*16 + lr;
#pragma unroll
            for (int r = 0; r < 4; ++r)
                C[(size_t)(row + r)*HIDDIM + col] = acc[mi][nj][r];
        }
    }
}

// ---------------- quadratic causal attention, paired 64-row q-tiles ----------------
// Balance fix: block handles tiles (31-p) and (p) -> exactly 33 chunks per block.
// grid = 16 pairs x 16 heads = 256 blocks (1/CU), 512 threads = 8 waves.
// sS rows wave-private (r8 cross-wave split regressed; r9 XCD swizzle <= neutral).
__global__ __launch_bounds__(512, 2) void attn(const bf16* __restrict__ qb,
                                               const bf16* __restrict__ kb,
                                               const bf16* __restrict__ vt,
                                               bf16* __restrict__ ob)
{
    __shared__ __attribute__((aligned(16))) bf16 sK[2*64*136];   // per-buf [s][d], pad 8
    __shared__ __attribute__((aligned(16))) bf16 sV[2*128*72];   // per-buf [d][s], pad 8
    __shared__ __attribute__((aligned(16))) bf16 sS[2*64*72];    // per-group [q][s], pad 8
    __shared__ __attribute__((aligned(16))) float sO[64*129];    // combine scratch, pad 1
    __shared__ __attribute__((aligned(16))) float sZ[64*17];

    const int h    = blockIdx.y;
    const int pr   = blockIdx.x;              // pair index 0..15
    const int tid  = threadIdx.x, lane = tid & 63;
    const int w    = tid >> 6;                // 0..7
    const int g    = w >> 2;                  // chunk group 0/1
    const int ww   = w & 3;                   // wave within group
    const int quad = lane >> 4, lr = lane & 15;
    const int rs   = tid >> 4;                // staging row 0..31 (x4 passes)
    const int cs   = (tid & 15) * 8;          // staging col 0..120

#pragma unroll
    for (int ti = 0; ti < 2; ++ti) {
        const int tile = ti ? pr : (31 - pr);
        const int nch  = tile + 1;

        // Q fragments (A-layout): wave owns q-rows [tile*64 + ww*16, +16)
        v8bf qa[4];
        {
            const bf16* q0 = qb + (size_t)(tile*64 + ww*16 + lr)*HIDDIM + h*HDIM + quad*8;
#pragma unroll
            for (int ks = 0; ks < 4; ++ks)
                qa[ks] = *(const v8bf*)(q0 + ks*32);
        }

        v4f  o[8] = {};
        float z[4] = {0.f, 0.f, 0.f, 0.f};

        v8bf curK[4], curV[4], nxtK[4], nxtV[4];
#pragma unroll
        for (int p = 0; p < 4; ++p) {
            curK[p] = *(const v8bf*)(kb + (size_t)(rs + p*32)*HIDDIM + h*HDIM + cs);
            curV[p] = *(const v8bf*)(vt + (size_t)(h*HDIM + rs + p*32)*HIDDIM + cs);
        }

        for (int ich = 0; ich < nch; ich += 2) {
            __syncthreads();                  // prev-chunk LDS reads done
#pragma unroll
            for (int p = 0; p < 4; ++p) {
                const int r = rs + p*32;      // kv row within pair [0,128)
                *(v8bf*)&sK[(r>>6)*8704 + (r&63)*136 + cs] = curK[p];
            }
#pragma unroll
            for (int p = 0; p < 4; ++p)       // cs selects buffer (col>=64 -> buf 1)
                *(v8bf*)&sV[(cs>>6)*9216 + (rs + p*32)*72 + (cs & 63)] = curV[p];

            if (ich + 2 < nch) {              // prefetch next pair (overlaps compute)
                const int s1 = (ich + 2) * 64;
#pragma unroll
                for (int p = 0; p < 4; ++p) {
                    nxtK[p] = *(const v8bf*)(kb + (size_t)(s1 + rs + p*32)*HIDDIM + h*HDIM + cs);
                    nxtV[p] = *(const v8bf*)(vt + (size_t)(h*HDIM + rs + p*32)*HIDDIM + s1 + cs);
                }
            }
            __syncthreads();                  // tiles visible

            const int ch = ich + g;
            if (ch < nch) {
                const bf16* sKg = &sK[g*8704];
                const bf16* sVg = &sV[g*9216];
                bf16*       sSg = &sS[g*4608];
                const bool  diag = (ch == tile);
                const int   s0   = ch * 64;

                // QK^T -> square/mask -> z, sS (sS rows wave-private)
                v8bf kbf[4][4];
#pragma unroll
                for (int nj = 0; nj < 4; ++nj)
#pragma unroll
                    for (int ks = 0; ks < 4; ++ks)
                        kbf[nj][ks] = *(const v8bf*)&sKg[(nj*16 + lr)*136 + ks*32 + quad*8];
                const int row_l = ww*16 + quad*4;
                const int qg    = tile*64 + row_l;
#pragma unroll
                for (int nj = 0; nj < 4; ++nj) {
                    v4f s4 = {0.f, 0.f, 0.f, 0.f};
#pragma unroll
                    for (int ks = 0; ks < 4; ++ks)
                        s4 = __builtin_amdgcn_mfma_f32_16x16x32_bf16(qa[ks], kbf[nj][ks], s4, 0, 0, 0);
                    const int col = nj*16 + lr;
                    const int sg  = s0 + col;
#pragma unroll
                    for (int r = 0; r < 4; ++r) {
                        float val = s4[r] * s4[r];
                        if (diag && (sg > qg + r)) val = 0.0f;
                        const bf16 vb16 = (bf16)val;
                        z[r] += (float)vb16;           // consistent with what multiplies V
                        sSg[(row_l + r)*72 + col] = vb16;
                    }
                }

                // O += S * V
#pragma unroll
                for (int ks = 0; ks < 2; ++ks) {
                    const v8bf sa = *(const v8bf*)&sSg[(ww*16 + lr)*72 + ks*32 + quad*8];
#pragma unroll
                    for (int nd = 0; nd < 8; ++nd) {
                        const v8bf vbf = *(const v8bf*)&sVg[(nd*16 + lr)*72 + ks*32 + quad*8];
                        o[nd] = __builtin_amdgcn_mfma_f32_16x16x32_bf16(sa, vbf, o[nd], 0, 0, 0);
                    }
                }
            }

            if (ich + 2 < nch) {
#pragma unroll
                for (int p = 0; p < 4; ++p) { curK[p] = nxtK[p]; curV[p] = nxtV[p]; }
            }
        }

        // cross-group combine: group 1 dumps partial O,z; group 0 adds + epilogue.
        const int row_l = ww*16 + quad*4;
        __syncthreads();
        if (g == 1) {
#pragma unroll
            for (int nd = 0; nd < 8; ++nd)
#pragma unroll
                for (int r = 0; r < 4; ++r)
                    sO[(row_l + r)*129 + nd*16 + lr] = o[nd][r];
#pragma unroll
            for (int r = 0; r < 4; ++r)
                sZ[(row_l + r)*17 + lr] = z[r];
        }
        __syncthreads();
        if (g == 0) {
#pragma unroll
            for (int nd = 0; nd < 8; ++nd)
#pragma unroll
                for (int r = 0; r < 4; ++r)
                    o[nd][r] += sO[(row_l + r)*129 + nd*16 + lr];
#pragma unroll
            for (int r = 0; r < 4; ++r) {
                float zz = z[r] + sZ[(row_l + r)*17 + lr];
                zz += __shfl_xor(zz, 1); zz += __shfl_xor(zz, 2);
                zz += __shfl_xor(zz, 4); zz += __shfl_xor(zz, 8);
                z[r] = zz + 1e-5f;
            }
            const size_t rbase = (size_t)(tile*64 + row_l)*HIDDIM + h*HDIM;
#pragma unroll
            for (int nd = 0; nd < 8; ++nd) {
                const int col = nd*16 + lr;
#pragma unroll
                for (int r = 0; r < 4; ++r)
                    ob[rbase + (size_t)r*HIDDIM + col] = (bf16)(o[nd][r] / z[r]);
            }
        }
    }
}

extern "C" void kernel_launch(void* const* d_in, const int* in_sizes, int n_in,
                              void* d_out, int out_size, void* d_ws, size_t ws_size,
                              hipStream_t stream)
{
    const float* hs    = (const float*)d_in[0];
    const float* Wq    = (const float*)d_in[1];
    const float* Wk    = (const float*)d_in[2];
    const float* Wv    = (const float*)d_in[3];
    const float* Wo    = (const float*)d_in[4];
    const float* gamma = (const float*)d_in[5];
    const float* beta  = (const float*)d_in[6];
    float* outp = (float*)d_out;

    const size_t MAT = (size_t)TSEQ * HIDDIM;     // 4.19M elems

    // ws layout (6 bf16 slots of 8.39 MB): hs_b(0), Wcat(1-3, q/k/v contiguous),
    // Wo_b(4), vt(5). qb/kb live in d_out (dead once gemm_out overwrites it with the
    // final fp32 output). ob aliases hs_b (dead after gemm_qkv384). fmap + transpose
    // are fused into gemm_qkv384's epilogue.
    bf16* ws   = (bf16*)d_ws;
    bf16* hs_b = ws + 0*MAT;
    bf16* ob   = hs_b;                            // alias: hs_b dead after gemm_qkv384
    bf16* Wq_b = ws + 1*MAT;                      // Wcat base
    bf16* Wk_b = ws + 2*MAT;
    bf16* Wv_b = ws + 3*MAT;
    bf16* Wo_b = ws + 4*MAT;
    bf16* vt   = ws + 5*MAT;
    bf16* qb   = (bf16*)d_out;
    bf16* kb   = (bf16*)d_out + MAT;

    conv5<<<dim3(2048, 5), 256, 0, stream>>>(hs, hs_b, Wq, Wq_b, Wk, Wk_b, Wv, Wv_b, Wo, Wo_b);
    gemm_qkv384<<<dim3(16, 16), 512, 0, stream>>>(hs_b, Wq_b, qb, kb, vt, gamma, beta);
    attn<<<dim3(16, 16), 512, 0, stream>>>(qb, kb, vt, ob);
    gemm_out<<<dim3(16, 16), 512, 0, stream>>>(ob, Wo_b, outp);
}